// Round 1
// baseline (375.229 us; speedup 1.0000x reference)
//
#include <hip/hip_runtime.h>

typedef unsigned short u16;
typedef __attribute__((ext_vector_type(8))) short bf16x8;
typedef __attribute__((ext_vector_type(8))) unsigned short u16x8;
typedef __attribute__((ext_vector_type(4))) float f32x4;

static __device__ __forceinline__ u16 f2bf(float f) {
  unsigned u = __float_as_uint(f);
  u += 0x7FFFu + ((u >> 16) & 1u);   // RNE
  return (u16)(u >> 16);
}
static __device__ __forceinline__ float bf2f(u16 h) {
  return __uint_as_float(((unsigned)h) << 16);
}

// ---------------- fp32 -> bf16 convert, 8 elems/thread ----------------
__global__ __launch_bounds__(256) void f2bf_vec(const float* __restrict__ in,
                                                u16* __restrict__ out, int n8) {
  int i = blockIdx.x * 256 + threadIdx.x;
  if (i >= n8) return;
  const float4* p = (const float4*)in + (size_t)i * 2;
  float4 a = p[0], b = p[1];
  u16x8 r;
  r[0] = f2bf(a.x); r[1] = f2bf(a.y); r[2] = f2bf(a.z); r[3] = f2bf(a.w);
  r[4] = f2bf(b.x); r[5] = f2bf(b.y); r[6] = f2bf(b.z); r[7] = f2bf(b.w);
  ((u16x8*)out)[i] = r;
}

// ---------------- row-sum of K (bf16, 1024 cols) -> fp32 ----------------
__global__ __launch_bounds__(256) void ksum_kernel(const u16* __restrict__ K,
                                                   float* __restrict__ out) {
  int row = blockIdx.x * 4 + (threadIdx.x >> 6);
  int lane = threadIdx.x & 63;
  const u16x8* p = (const u16x8*)(K + (size_t)row * 1024);
  float s = 0.f;
#pragma unroll
  for (int it = 0; it < 2; ++it) {
    u16x8 v = p[lane + it * 64];
#pragma unroll
    for (int j = 0; j < 8; ++j) s += bf2f(v[j]);
  }
#pragma unroll
  for (int off = 32; off >= 1; off >>= 1) s += __shfl_down(s, off);
  if (lane == 0) out[row] = s;
}

// ---------------- generic 128x128 bf16 GEMM, C = A(MxK) * B(NxK)^T ----------------
// XOR-swizzled LDS (write side: pre-swizzled global source for global_load_lds;
// read side: same XOR on ds_read addr). 4 waves, each owns 64x64 of C.
enum { M_BIASN = 0, M_BIASM = 1, M_SCORES = 2, M_OUT = 3 };

template <int MODE>
__global__ __launch_bounds__(256) void gemm_bt(
    const u16* __restrict__ A, int lda, long long sA,
    const u16* __restrict__ B, int ldb, long long sB,
    void* __restrict__ Cv, int ldc, long long sC,
    int k_len, const float* __restrict__ bias,
    const float* __restrict__ ksum, const float* __restrict__ vtab, int Tdim) {
  const int gx = blockIdx.x, gy = blockIdx.y, z = blockIdx.z;
  if (MODE == M_SCORES && gx > gy) return;  // upper-triangle tiles never read
  const int kl = (MODE == M_OUT) ? (gy + 1) * 128 : k_len;  // causal K-extent

  const u16* Ab = A + (size_t)z * sA;
  const u16* Bb = B + (size_t)z * sB;
  const int m0 = gy * 128, n0 = gx * 128;

  __shared__ char smem[32768];
  char* As = smem;
  char* Bs = smem + 16384;

  const int tid = threadIdx.x;
  const int lane = tid & 63;
  const int wid = tid >> 6;
  const int wm = wid >> 1, wn = wid & 1;

  f32x4 acc[4][4];
#pragma unroll
  for (int m = 0; m < 4; ++m)
#pragma unroll
    for (int n = 0; n < 4; ++n) acc[m][n] = (f32x4){0.f, 0.f, 0.f, 0.f};

  // staging geometry: per issue, 256 threads move 4KB; LDS dest is linear,
  // global source carries the inverse XOR swizzle (involution).
  int srow[4], scol[4];
#pragma unroll
  for (int i = 0; i < 4; ++i) {
    int f = tid * 16 + i * 4096;
    int row = f >> 7;         // 128B per 64-col bf16 row
    int cb = f & 127;
    srow[i] = row;
    scol[i] = cb ^ ((row & 7) << 4);
  }

  const int nk = kl >> 6;
  for (int kt = 0; kt < nk; ++kt) {
    const int k0 = kt * 64;
#pragma unroll
    for (int i = 0; i < 4; ++i) {
      const char* ga = (const char*)(Ab + (size_t)(m0 + srow[i]) * lda + k0) + scol[i];
      const char* gb = (const char*)(Bb + (size_t)(n0 + srow[i]) * ldb + k0) + scol[i];
      __builtin_amdgcn_global_load_lds(
          (const __attribute__((address_space(1))) void*)ga,
          (__attribute__((address_space(3))) void*)(As + wid * 1024 + i * 4096), 16, 0, 0);
      __builtin_amdgcn_global_load_lds(
          (const __attribute__((address_space(1))) void*)gb,
          (__attribute__((address_space(3))) void*)(Bs + wid * 1024 + i * 4096), 16, 0, 0);
    }
    __syncthreads();
#pragma unroll
    for (int ks = 0; ks < 2; ++ks) {
      bf16x8 af[4], bfv[4];
      const int kb = ks * 64 + ((lane >> 4) << 4);
#pragma unroll
      for (int m = 0; m < 4; ++m) {
        int r = wm * 64 + m * 16 + (lane & 15);
        af[m] = *(const bf16x8*)(As + r * 128 + (kb ^ ((r & 7) << 4)));
      }
#pragma unroll
      for (int n = 0; n < 4; ++n) {
        int r = wn * 64 + n * 16 + (lane & 15);
        bfv[n] = *(const bf16x8*)(Bs + r * 128 + (kb ^ ((r & 7) << 4)));
      }
#pragma unroll
      for (int m = 0; m < 4; ++m)
#pragma unroll
        for (int n = 0; n < 4; ++n)
          acc[m][n] = __builtin_amdgcn_mfma_f32_16x16x32_bf16(af[m], bfv[n], acc[m][n], 0, 0, 0);
    }
    __syncthreads();
  }

  // epilogue — C/D layout: col = lane&15, row = (lane>>4)*4 + reg  [m89-verified]
  const float* ksb = (MODE == M_SCORES) ? (ksum + (size_t)z * Tdim) : nullptr;
  u16* Cb16 = (u16*)Cv + (size_t)z * sC;
  float* Cf = (float*)Cv + (size_t)z * sC;

#pragma unroll
  for (int m = 0; m < 4; ++m) {
#pragma unroll
    for (int n = 0; n < 4; ++n) {
      const int rbase = m0 + wm * 64 + m * 16 + ((lane >> 4) << 2);
      const int c = n0 + wn * 64 + n * 16 + (lane & 15);
#pragma unroll
      for (int j = 0; j < 4; ++j) {
        const int r = rbase + j;
        float v = acc[m][n][j];
        if (MODE == M_BIASN) {
          v += bias[c];
          Cb16[(size_t)r * ldc + c] = f2bf(v);
        } else if (MODE == M_BIASM) {
          v += bias[r];
          Cb16[(size_t)r * ldc + c] = f2bf(v);
        } else if (MODE == M_SCORES) {
          if (c <= r) v += ksb[r] * vtab[r - c];  // rel = t-s >= 0 in kept region
          else v = 0.f;                           // causal mask
          Cb16[(size_t)r * ldc + c] = f2bf(v);
        } else {  // M_OUT
          Cf[(size_t)r * ldc + c] = v;
        }
      }
    }
  }
}

extern "C" void kernel_launch(void* const* d_in, const int* in_sizes, int n_in,
                              void* d_out, int out_size, void* d_ws, size_t ws_size,
                              hipStream_t stream) {
  (void)in_sizes; (void)n_in; (void)out_size; (void)ws_size;
  const float* e    = (const float*)d_in[0];
  const float* res  = (const float*)d_in[1];
  const float* Wq_w = (const float*)d_in[2];
  const float* Wq_b = (const float*)d_in[3];
  const float* Wk_w = (const float*)d_in[4];
  const float* Wk_b = (const float*)d_in[5];
  const float* Wv_w = (const float*)d_in[6];
  const float* Wv_b = (const float*)d_in[7];
  const float* vtab = (const float*)d_in[8];

  const int T = 2048, D = 1024, Bn = 8;
  const size_t BT = (size_t)Bn * T;     // 16384
  const size_t ND = BT * (size_t)D;     // 16,777,216 elements

  char* ws = (char*)d_ws;
  const size_t SZ = 33554432;  // 32 MiB = one bf16 (16384x1024) buffer
  u16* ebf = (u16*)(ws);
  u16* rbf = (u16*)(ws + SZ);
  u16* Qb  = (u16*)(ws + 2 * SZ);
  u16* Kb  = (u16*)(ws + 3 * SZ);
  u16* VT  = (u16*)(ws + 4 * SZ);
  u16* Wqb = (u16*)(ws + 5 * SZ);
  u16* Wkb = (u16*)(ws + 5 * SZ + 2097152);
  u16* Wvb = (u16*)(ws + 5 * SZ + 2 * 2097152);
  float* ksum = (float*)(ws + 5 * SZ + 3 * 2097152);
  u16* scores = (u16*)(ws);  // reuse ebf+rbf (67 MB), safe: last read is VT gemm

  // fp32 -> bf16
  f2bf_vec<<<(int)(ND / 8 / 256), 256, 0, stream>>>(e, ebf, (int)(ND / 8));
  f2bf_vec<<<(int)(ND / 8 / 256), 256, 0, stream>>>(res, rbf, (int)(ND / 8));
  f2bf_vec<<<512, 256, 0, stream>>>(Wq_w, Wqb, 131072);
  f2bf_vec<<<512, 256, 0, stream>>>(Wk_w, Wkb, 131072);
  f2bf_vec<<<512, 256, 0, stream>>>(Wv_w, Wvb, 131072);

  // Q = e @ Wq^T + bq   (16384x1024)
  gemm_bt<M_BIASN><<<dim3(8, 128, 1), 256, 0, stream>>>(
      ebf, D, 0, Wqb, D, 0, (void*)Qb, D, 0, D, Wq_b, nullptr, nullptr, T);
  // K = res @ Wk^T + bk
  gemm_bt<M_BIASN><<<dim3(8, 128, 1), 256, 0, stream>>>(
      rbf, D, 0, Wkb, D, 0, (void*)Kb, D, 0, D, Wk_b, nullptr, nullptr, T);
  // V^T[d, b*T+t] = Wv @ e^T + bv (bias per row d) -> coalesced stores, and
  // gives pass-B its (N x K) K-contiguous operand for free.
  gemm_bt<M_BIASM><<<dim3(128, 8, 1), 256, 0, stream>>>(
      Wvb, D, 0, ebf, D, 0, (void*)VT, (int)BT, 0, D, Wv_b, nullptr, nullptr, T);

  // Ksum[b,t]
  ksum_kernel<<<4096, 256, 0, stream>>>(Kb, ksum);

  // scores[b,t,s] = Q.K^T + Ksum[t]*v[t-s], causal, bf16 (lower-tri tiles only)
  gemm_bt<M_SCORES><<<dim3(16, 16, 8), 256, 0, stream>>>(
      Qb, D, (long long)T * D, Kb, D, (long long)T * D, (void*)scores, T,
      (long long)T * T, D, nullptr, ksum, vtab, T);

  // out[b,t,d] = scores @ V  (k truncated at causal boundary), fp32
  gemm_bt<M_OUT><<<dim3(8, 16, 8), 256, 0, stream>>>(
      scores, T, (long long)T * T, VT, (int)BT, T, d_out, D, (long long)T * D,
      0, nullptr, nullptr, nullptr, T);
}

// Round 2
// 334.712 us; speedup vs baseline: 1.1211x; 1.1211x over previous
//
#include <hip/hip_runtime.h>

typedef unsigned short u16;
typedef __attribute__((ext_vector_type(8))) short bf16x8;
typedef __attribute__((ext_vector_type(8))) unsigned short u16x8;
typedef __attribute__((ext_vector_type(4))) float f32x4;

static __device__ __forceinline__ u16 f2bf(float f) {
  unsigned u = __float_as_uint(f);
  u += 0x7FFFu + ((u >> 16) & 1u);   // RNE
  return (u16)(u >> 16);
}
static __device__ __forceinline__ float bf2f(u16 h) {
  return __uint_as_float(((unsigned)h) << 16);
}

// ---------------- fp32 -> bf16 convert, 8 elems/thread ----------------
__global__ __launch_bounds__(256) void f2bf_vec(const float* __restrict__ in,
                                                u16* __restrict__ out, int n8) {
  int i = blockIdx.x * 256 + threadIdx.x;
  if (i >= n8) return;
  const float4* p = (const float4*)in + (size_t)i * 2;
  float4 a = p[0], b = p[1];
  u16x8 r;
  r[0] = f2bf(a.x); r[1] = f2bf(a.y); r[2] = f2bf(a.z); r[3] = f2bf(a.w);
  r[4] = f2bf(b.x); r[5] = f2bf(b.y); r[6] = f2bf(b.z); r[7] = f2bf(b.w);
  ((u16x8*)out)[i] = r;
}

// ---------------- row-sum of K (bf16, 1024 cols) -> fp32 ----------------
__global__ __launch_bounds__(256) void ksum_kernel(const u16* __restrict__ K,
                                                   float* __restrict__ out) {
  int row = blockIdx.x * 4 + (threadIdx.x >> 6);
  int lane = threadIdx.x & 63;
  const u16x8* p = (const u16x8*)(K + (size_t)row * 1024);
  float s = 0.f;
#pragma unroll
  for (int it = 0; it < 2; ++it) {
    u16x8 v = p[lane + it * 64];
#pragma unroll
    for (int j = 0; j < 8; ++j) s += bf2f(v[j]);
  }
#pragma unroll
  for (int off = 32; off >= 1; off >>= 1) s += __shfl_down(s, off);
  if (lane == 0) out[row] = s;
}

// =============== 256x256 bf16 GEMM engine, C = A(MxK) * B(NxK)^T ===============
// 8 waves (2M x 4N), BK=64, double-buffered 128KB LDS, counted vmcnt(8) so the
// next tile's global_load_lds stay in flight across the barrier (T3+T4), XOR
// swizzle st-style on LDS reads with inverse-swizzled global source (T2).
enum { M_BIASN = 0, M_BIASM = 1, M_SCORES = 2, M_OUT = 3 };

template <int MODE>
__global__ __launch_bounds__(512, 2) void gemm_bt(
    const u16* __restrict__ A, int lda, long long sA,
    const u16* __restrict__ B, int ldb, long long sB,
    void* __restrict__ Cv, int ldc, long long sC,
    int k_len, const float* __restrict__ bias,
    const float* __restrict__ ksum, const float* __restrict__ vtab, int Tdim) {
  // ---- bijective XCD swizzle (nl % 8 == 0 for all our grids) ----
  const int nl = gridDim.x * gridDim.y;
  const int l = blockIdx.x + gridDim.x * blockIdx.y;
  const int q8 = nl >> 3;
  const int logical = (l & 7) * q8 + (l >> 3);
  const int gx = logical % gridDim.x;
  const int gy = logical / gridDim.x;
  const int z = blockIdx.z;

  if (MODE == M_SCORES && gx > gy) return;  // upper-triangle tiles never read
  const int kl = (MODE == M_OUT) ? (gy + 1) * 256 : k_len;  // causal K-extent

  const u16* Ab = A + (size_t)z * sA;
  const u16* Bb = B + (size_t)z * sB;
  const int m0 = gy * 256, n0 = gx * 256;

  __shared__ char smem[131072];  // 2 x (A 32KB + B 32KB)

  const int tid = threadIdx.x;
  const int lane = tid & 63;
  const int wid = tid >> 6;
  const int wm = wid >> 2, wn = wid & 3;  // 2 x 4 wave grid, wave owns 128x64

  f32x4 acc[8][4];
#pragma unroll
  for (int m = 0; m < 8; ++m)
#pragma unroll
    for (int n = 0; n < 4; ++n) acc[m][n] = (f32x4){0.f, 0.f, 0.f, 0.f};

  // staging geometry: 4 issues/matrix, 512 thr x 16B = 8KB per issue.
  // LDS dest linear; global source column carries the inverse XOR swizzle.
  int srow[4], scol[4];
#pragma unroll
  for (int i = 0; i < 4; ++i) {
    int f = tid * 16 + i * 8192;
    int row = f >> 7;  // 128B per 64-col bf16 row
    int cb = f & 127;
    srow[i] = row;
    scol[i] = cb ^ ((row & 7) << 4);
  }

#define STAGE(kt_, buf_)                                                        \
  {                                                                             \
    const int k0_ = (kt_) * 64;                                                 \
    char* As_ = smem + (buf_) * 65536;                                          \
    char* Bs_ = As_ + 32768;                                                    \
    _Pragma("unroll") for (int i = 0; i < 4; ++i) {                             \
      const char* ga = (const char*)(Ab + (size_t)(m0 + srow[i]) * lda + k0_) + scol[i]; \
      const char* gb = (const char*)(Bb + (size_t)(n0 + srow[i]) * ldb + k0_) + scol[i]; \
      __builtin_amdgcn_global_load_lds(                                         \
          (const __attribute__((address_space(1))) void*)ga,                    \
          (__attribute__((address_space(3))) void*)(As_ + i * 8192 + wid * 1024), 16, 0, 0); \
      __builtin_amdgcn_global_load_lds(                                         \
          (const __attribute__((address_space(1))) void*)gb,                    \
          (__attribute__((address_space(3))) void*)(Bs_ + i * 8192 + wid * 1024), 16, 0, 0); \
    }                                                                           \
  }

  const int nk = kl >> 6;
  STAGE(0, 0);
  for (int kt = 0; kt < nk; ++kt) {
    const int cur = kt & 1;
    if (kt + 1 < nk) {
      STAGE(kt + 1, cur ^ 1);
      asm volatile("s_waitcnt vmcnt(8)" ::: "memory");  // tile kt complete; kt+1 in flight
    } else {
      asm volatile("s_waitcnt vmcnt(0)" ::: "memory");
    }
    __builtin_amdgcn_s_barrier();
    __builtin_amdgcn_sched_barrier(0);

    const char* As = smem + cur * 65536;
    const char* Bs = As + 32768;
#pragma unroll
    for (int ks = 0; ks < 2; ++ks) {
      const int kb = ks * 64 + ((lane >> 4) << 4);
      bf16x8 af[8], bfv[4];
#pragma unroll
      for (int m = 0; m < 8; ++m) {
        int r = wm * 128 + m * 16 + (lane & 15);
        af[m] = *(const bf16x8*)(As + r * 128 + (kb ^ ((r & 7) << 4)));
      }
#pragma unroll
      for (int n = 0; n < 4; ++n) {
        int r = wn * 64 + n * 16 + (lane & 15);
        bfv[n] = *(const bf16x8*)(Bs + r * 128 + (kb ^ ((r & 7) << 4)));
      }
#pragma unroll
      for (int m = 0; m < 8; ++m)
#pragma unroll
        for (int n = 0; n < 4; ++n)
          acc[m][n] = __builtin_amdgcn_mfma_f32_16x16x32_bf16(af[m], bfv[n], acc[m][n], 0, 0, 0);
    }
    asm volatile("s_waitcnt lgkmcnt(0)" ::: "memory");
    __builtin_amdgcn_sched_barrier(0);
    __builtin_amdgcn_s_barrier();  // reads of buf[cur] done -> next iter may restage it
  }
#undef STAGE

  // epilogue — C/D layout: col = lane&15, row = (lane>>4)*4 + reg  [m89-verified]
  const float* ksb = (MODE == M_SCORES) ? (ksum + (size_t)z * Tdim) : nullptr;
  u16* Cb16 = (u16*)Cv + (size_t)z * sC;
  float* Cf = (float*)Cv + (size_t)z * sC;

#pragma unroll
  for (int m = 0; m < 8; ++m) {
#pragma unroll
    for (int n = 0; n < 4; ++n) {
      const int rbase = m0 + wm * 128 + m * 16 + ((lane >> 4) << 2);
      const int c = n0 + wn * 64 + n * 16 + (lane & 15);
#pragma unroll
      for (int j = 0; j < 4; ++j) {
        const int r = rbase + j;
        float v = acc[m][n][j];
        if (MODE == M_BIASN) {
          v += bias[c];
          Cb16[(size_t)r * ldc + c] = f2bf(v);
        } else if (MODE == M_BIASM) {
          v += bias[r];
          Cb16[(size_t)r * ldc + c] = f2bf(v);
        } else if (MODE == M_SCORES) {
          if (c <= r) v += ksb[r] * vtab[r - c];  // rel = t-s >= 0 in kept region
          else v = 0.f;                           // causal mask
          Cb16[(size_t)r * ldc + c] = f2bf(v);
        } else {  // M_OUT
          Cf[(size_t)r * ldc + c] = v;
        }
      }
    }
  }
}

extern "C" void kernel_launch(void* const* d_in, const int* in_sizes, int n_in,
                              void* d_out, int out_size, void* d_ws, size_t ws_size,
                              hipStream_t stream) {
  (void)in_sizes; (void)n_in; (void)out_size; (void)ws_size;
  const float* e    = (const float*)d_in[0];
  const float* res  = (const float*)d_in[1];
  const float* Wq_w = (const float*)d_in[2];
  const float* Wq_b = (const float*)d_in[3];
  const float* Wk_w = (const float*)d_in[4];
  const float* Wk_b = (const float*)d_in[5];
  const float* Wv_w = (const float*)d_in[6];
  const float* Wv_b = (const float*)d_in[7];
  const float* vtab = (const float*)d_in[8];

  const int T = 2048, D = 1024, Bn = 8;
  const size_t BT = (size_t)Bn * T;     // 16384
  const size_t ND = BT * (size_t)D;     // 16,777,216 elements

  char* ws = (char*)d_ws;
  const size_t SZ = 33554432;  // 32 MiB = one bf16 (16384x1024) buffer
  u16* ebf = (u16*)(ws);
  u16* rbf = (u16*)(ws + SZ);
  u16* Qb  = (u16*)(ws + 2 * SZ);
  u16* Kb  = (u16*)(ws + 3 * SZ);
  u16* VT  = (u16*)(ws + 4 * SZ);
  u16* Wqb = (u16*)(ws + 5 * SZ);
  u16* Wkb = (u16*)(ws + 5 * SZ + 2097152);
  u16* Wvb = (u16*)(ws + 5 * SZ + 2 * 2097152);
  float* ksum = (float*)(ws + 5 * SZ + 3 * 2097152);
  u16* scores = (u16*)(ws);  // reuse ebf+rbf (67 MB), safe: last read is VT gemm

  // fp32 -> bf16
  f2bf_vec<<<(int)(ND / 8 / 256), 256, 0, stream>>>(e, ebf, (int)(ND / 8));
  f2bf_vec<<<(int)(ND / 8 / 256), 256, 0, stream>>>(res, rbf, (int)(ND / 8));
  f2bf_vec<<<512, 256, 0, stream>>>(Wq_w, Wqb, 131072);
  f2bf_vec<<<512, 256, 0, stream>>>(Wk_w, Wkb, 131072);
  f2bf_vec<<<512, 256, 0, stream>>>(Wv_w, Wvb, 131072);

  // Q = e @ Wq^T + bq   (16384x1024), 256^2 tiles -> grid (4, 64)
  gemm_bt<M_BIASN><<<dim3(4, 64, 1), 512, 0, stream>>>(
      ebf, D, 0, Wqb, D, 0, (void*)Qb, D, 0, D, Wq_b, nullptr, nullptr, T);
  // K = res @ Wk^T + bk
  gemm_bt<M_BIASN><<<dim3(4, 64, 1), 512, 0, stream>>>(
      rbf, D, 0, Wkb, D, 0, (void*)Kb, D, 0, D, Wk_b, nullptr, nullptr, T);
  // V^T[d, b*T+t] = Wv @ e^T + bv (bias per row d) -> coalesced stores; gives
  // the out-pass its (N x K) K-contiguous B operand.
  gemm_bt<M_BIASM><<<dim3(64, 4, 1), 512, 0, stream>>>(
      Wvb, D, 0, ebf, D, 0, (void*)VT, (int)BT, 0, D, Wv_b, nullptr, nullptr, T);

  // Ksum[b,t]
  ksum_kernel<<<4096, 256, 0, stream>>>(Kb, ksum);

  // scores[b,t,s] = Q.K^T + Ksum[t]*v[t-s], causal, bf16 (lower-tri tiles only)
  gemm_bt<M_SCORES><<<dim3(8, 8, 8), 512, 0, stream>>>(
      Qb, D, (long long)T * D, Kb, D, (long long)T * D, (void*)scores, T,
      (long long)T * T, D, nullptr, ksum, vtab, T);

  // out[b,t,d] = scores @ V  (k truncated at causal boundary), fp32
  gemm_bt<M_OUT><<<dim3(4, 8, 8), 512, 0, stream>>>(
      scores, T, (long long)T * T, VT, (int)BT, T, d_out, D, (long long)T * D,
      0, nullptr, nullptr, nullptr, T);
}